// Round 1
// baseline (678.480 us; speedup 1.0000x reference)
//
#include <hip/hip_runtime.h>
#include <cmath>

typedef __bf16 bf16;
typedef __bf16 bf16x8 __attribute__((ext_vector_type(8)));
typedef __bf16 bf16x4 __attribute__((ext_vector_type(4)));
typedef float  f32x4  __attribute__((ext_vector_type(4)));
typedef unsigned int u32x4 __attribute__((ext_vector_type(4)));

#define MFMA16(a, b, c) __builtin_amdgcn_mfma_f32_16x16x32_bf16((a), (b), (c), 0, 0, 0)

static __device__ __forceinline__ bf16x8 bneg8(bf16x8 x) {
    u32x4 u = __builtin_bit_cast(u32x4, x);
    u = u ^ 0x80008000u;
    return __builtin_bit_cast(bf16x8, u);
}

static __device__ __forceinline__ f32x4 zero4() {
    return f32x4{0.0f, 0.0f, 0.0f, 0.0f};
}

// ---------------------------------------------------------------------------
// small utility kernels
// ---------------------------------------------------------------------------
__global__ void fill_kernel(float* p, float v, int n) {
    for (int i = blockIdx.x * blockDim.x + threadIdx.x; i < n; i += gridDim.x * blockDim.x)
        p[i] = v;
}

__global__ void splitx_kernel(const float2* __restrict__ x, float* __restrict__ xr,
                              float* __restrict__ xi, int n) {
    for (int i = blockIdx.x * blockDim.x + threadIdx.x; i < n; i += gridDim.x * blockDim.x) {
        float2 v = x[i];
        xr[i] = v.x;
        xi[i] = v.y;
    }
}

__global__ void cvt_kernel(const float* __restrict__ in, bf16* __restrict__ out, int n) {
    for (int i = blockIdx.x * blockDim.x + threadIdx.x; i < n; i += gridDim.x * blockDim.x)
        out[i] = (bf16)in[i];
}

// ---------------------------------------------------------------------------
// complex magnitude layernorm: planes (f32) -> bf16 planes
// one block per row (768 features, 256 threads x 3)
// ---------------------------------------------------------------------------
__global__ __launch_bounds__(256) void cln_kernel(
    const float* __restrict__ xr, const float* __restrict__ xi,
    const float* __restrict__ gamma, const float* __restrict__ beta,
    bf16* __restrict__ nr, bf16* __restrict__ ni) {
    __shared__ float red[4];
    const int t = threadIdx.x;
    const size_t base = (size_t)blockIdx.x * 768;

    float r[3], im[3], mg[3];
#pragma unroll
    for (int j = 0; j < 3; ++j) {
        const int f = t + j * 256;
        r[j] = xr[base + f];
        im[j] = xi[base + f];
        mg[j] = sqrtf(r[j] * r[j] + im[j] * im[j] + 1e-6f);
    }
    float s = mg[0] + mg[1] + mg[2];
#pragma unroll
    for (int m = 32; m >= 1; m >>= 1) s += __shfl_xor(s, m);
    if ((t & 63) == 0) red[t >> 6] = s;
    __syncthreads();
    const float mean = (red[0] + red[1] + red[2] + red[3]) * (1.0f / 768.0f);
    __syncthreads();

    float v = 0.0f;
#pragma unroll
    for (int j = 0; j < 3; ++j) {
        const float d = mg[j] - mean;
        v += d * d;
    }
#pragma unroll
    for (int m = 32; m >= 1; m >>= 1) v += __shfl_xor(v, m);
    if ((t & 63) == 0) red[t >> 6] = v;
    __syncthreads();
    const float var = (red[0] + red[1] + red[2] + red[3]) * (1.0f / 768.0f);
    const float rstd = rsqrtf(var + 1e-6f);

#pragma unroll
    for (int j = 0; j < 3; ++j) {
        const int f = t + j * 256;
        const float sc = (mg[j] - mean) * rstd / (mg[j] + 1e-6f);
        nr[base + f] = (bf16)(gamma[2 * f] * (r[j] * sc) + beta[2 * f]);
        ni[base + f] = (bf16)(gamma[2 * f + 1] * (im[j] * sc) + beta[2 * f + 1]);
    }
}

// ---------------------------------------------------------------------------
// complex GEMM (NT): out[m,n] = sum_k A[m,k] * W[n,k] (complex)
// A: bf16 planes [M,K]; W: bf16 planes [N,K]; bias f32 [N]
// MODE 0: store bf16 planes
// MODE 1: f32 planes = res + out
// MODE 2: gelu(out+bias) -> bf16 planes
// MODE 3: interleaved f32 d_out[row*2N + 2c+{0,1}] = res + out
// ---------------------------------------------------------------------------
template <int MODE>
__global__ __launch_bounds__(256, 2) void cgemm_kernel(
    const bf16* __restrict__ Ar, const bf16* __restrict__ Ai,
    const bf16* __restrict__ Wr, const bf16* __restrict__ Wi,
    const float* __restrict__ br, const float* __restrict__ bi,
    const float* __restrict__ resr, const float* __restrict__ resi,
    float* __restrict__ outFr, float* __restrict__ outFi,
    bf16* __restrict__ outBr, bf16* __restrict__ outBi,
    int N, int K) {
    __shared__ bf16 sAr[128][32];
    __shared__ bf16 sAi[128][32];
    __shared__ bf16 sBr[128][32];
    __shared__ bf16 sBi[128][32];

    const int tid = threadIdx.x;
    const int wave = tid >> 6, lane = tid & 63;
    const int lg = lane >> 4, lr = lane & 15;
    const int row0 = blockIdx.x * 128, col0 = blockIdx.y * 128;
    const int wm = (wave >> 1) * 64, wn = (wave & 1) * 64;

    f32x4 accr[4][4], acci[4][4];
#pragma unroll
    for (int a = 0; a < 4; ++a)
#pragma unroll
        for (int b2 = 0; b2 < 4; ++b2) {
            accr[a][b2] = zero4();
            acci[a][b2] = zero4();
        }

    for (int kt = 0; kt < K; kt += 32) {
        __syncthreads();
#pragma unroll
        for (int j = 0; j < 2; ++j) {
            const int c = j * 256 + tid;
            const int rr = c >> 2;
            const int k8 = (c & 3) << 3;
            const size_t ga = (size_t)(row0 + rr) * K + kt + k8;
            const size_t gb = (size_t)(col0 + rr) * K + kt + k8;
            *(bf16x8*)(&sAr[rr][k8]) = *(const bf16x8*)(Ar + ga);
            *(bf16x8*)(&sAi[rr][k8]) = *(const bf16x8*)(Ai + ga);
            *(bf16x8*)(&sBr[rr][k8]) = *(const bf16x8*)(Wr + gb);
            *(bf16x8*)(&sBi[rr][k8]) = *(const bf16x8*)(Wi + gb);
        }
        __syncthreads();

        bf16x8 ar[4], ai[4], an[4];
#pragma unroll
        for (int mt = 0; mt < 4; ++mt) {
            ar[mt] = *(const bf16x8*)(&sAr[wm + mt * 16 + lr][lg * 8]);
            ai[mt] = *(const bf16x8*)(&sAi[wm + mt * 16 + lr][lg * 8]);
            an[mt] = bneg8(ai[mt]);
        }
#pragma unroll
        for (int nt = 0; nt < 4; ++nt) {
            const bf16x8 br8 = *(const bf16x8*)(&sBr[wn + nt * 16 + lr][lg * 8]);
            const bf16x8 bi8 = *(const bf16x8*)(&sBi[wn + nt * 16 + lr][lg * 8]);
#pragma unroll
            for (int mt = 0; mt < 4; ++mt) {
                accr[mt][nt] = MFMA16(ar[mt], br8, accr[mt][nt]);
                accr[mt][nt] = MFMA16(an[mt], bi8, accr[mt][nt]);
                acci[mt][nt] = MFMA16(ar[mt], bi8, acci[mt][nt]);
                acci[mt][nt] = MFMA16(ai[mt], br8, acci[mt][nt]);
            }
        }
    }

#pragma unroll
    for (int nt = 0; nt < 4; ++nt) {
        const int col = col0 + wn + nt * 16 + lr;
        const float bre = br[col], bie = bi[col];
#pragma unroll
        for (int mt = 0; mt < 4; ++mt) {
#pragma unroll
            for (int j = 0; j < 4; ++j) {
                const int row = row0 + wm + mt * 16 + lg * 4 + j;
                float vr = accr[mt][nt][j] + bre;
                float vi = acci[mt][nt][j] + bie;
                const size_t o = (size_t)row * N + col;
                if (MODE == 0) {
                    outBr[o] = (bf16)vr;
                    outBi[o] = (bf16)vi;
                } else if (MODE == 1) {
                    outFr[o] = resr[o] + vr;
                    outFi[o] = resi[o] + vi;
                } else if (MODE == 2) {
                    vr = 0.5f * vr * (1.0f + erff(vr * 0.70710678118654752f));
                    vi = 0.5f * vi * (1.0f + erff(vi * 0.70710678118654752f));
                    outBr[o] = (bf16)vr;
                    outBi[o] = (bf16)vi;
                } else {
                    const size_t ro = (size_t)row * 768 + col;
                    outFr[(size_t)row * 1536 + 2 * col]     = resr[ro] + vr;
                    outFr[(size_t)row * 1536 + 2 * col + 1] = resi[ro] + vi;
                }
            }
        }
    }
}

// ---------------------------------------------------------------------------
// transpose V slice of qkv into [B*nH][64 d][2048 n] bf16 planes
// ---------------------------------------------------------------------------
__global__ __launch_bounds__(256) void vtrans_kernel(
    const bf16* __restrict__ qkvr, const bf16* __restrict__ qkvi,
    bf16* __restrict__ vtr, bf16* __restrict__ vti) {
    __shared__ bf16 sr[64][65];
    __shared__ bf16 si[64][65];
    const int t = threadIdx.x;
    const int nb = blockIdx.x, h = blockIdx.y, b = blockIdx.z;
    const size_t ld = 2304;
    const bf16* srcr = qkvr + (size_t)(b * 2048 + nb * 64) * ld + 1536 + h * 64;
    const bf16* srci = qkvi + (size_t)(b * 2048 + nb * 64) * ld + 1536 + h * 64;
#pragma unroll
    for (int j = 0; j < 16; ++j) {
        const int idx = t + 256 * j;
        const int n = idx >> 6, d = idx & 63;
        sr[n][d] = srcr[(size_t)n * ld + d];
        si[n][d] = srci[(size_t)n * ld + d];
    }
    __syncthreads();
    bf16* dstr = vtr + (size_t)(b * 12 + h) * 64 * 2048 + nb * 64;
    bf16* dsti = vti + (size_t)(b * 12 + h) * 64 * 2048 + nb * 64;
#pragma unroll
    for (int j = 0; j < 16; ++j) {
        const int idx = t + 256 * j;
        const int d = idx >> 6, n = idx & 63;
        dstr[(size_t)d * 2048 + n] = sr[n][d];
        dsti[(size_t)d * 2048 + n] = si[n][d];
    }
}

// ---------------------------------------------------------------------------
// fused complex flash attention
// one wave per (b, h, 16 q-rows); online softmax over |S|/8
// ---------------------------------------------------------------------------
__global__ __launch_bounds__(64) void cattn_kernel(
    const bf16* __restrict__ qkvr, const bf16* __restrict__ qkvi,
    const bf16* __restrict__ vtr, const bf16* __restrict__ vti,
    bf16* __restrict__ aor, bf16* __restrict__ aoi) {
    const int lane = threadIdx.x;
    const int lg = lane >> 4, lr = lane & 15;
    const int qb = blockIdx.x, h = blockIdx.y, b = blockIdx.z;
    const size_t ld = 2304;
    __shared__ bf16 P[2][16][32];

    const size_t qoff = (size_t)(b * 2048 + qb * 16 + lr) * ld + h * 64;
    bf16x8 aqr[2], aqi[2], aqin[2];
#pragma unroll
    for (int ks = 0; ks < 2; ++ks) {
        aqr[ks] = *(const bf16x8*)(qkvr + qoff + ks * 32 + lg * 8);
        aqi[ks] = *(const bf16x8*)(qkvi + qoff + ks * 32 + lg * 8);
        aqin[ks] = bneg8(aqi[ks]);
    }
    const bf16* kbr = qkvr + (size_t)b * 2048 * ld + 768 + h * 64;
    const bf16* kbi = qkvi + (size_t)b * 2048 * ld + 768 + h * 64;
    const bf16* vbr = vtr + (size_t)(b * 12 + h) * 64 * 2048;
    const bf16* vbi = vti + (size_t)(b * 12 + h) * 64 * 2048;

    f32x4 our[4], oui[4];
#pragma unroll
    for (int d = 0; d < 4; ++d) {
        our[d] = zero4();
        oui[d] = zero4();
    }
    float mrun = -1e30f, lrun = 0.0f;

    for (int kt = 0; kt < 64; ++kt) {
        f32x4 str[2], sti[2];
        str[0] = zero4(); str[1] = zero4();
        sti[0] = zero4(); sti[1] = zero4();
#pragma unroll
        for (int t = 0; t < 2; ++t) {
            const size_t krow = (size_t)(kt * 32 + t * 16 + lr) * ld;
#pragma unroll
            for (int ks = 0; ks < 2; ++ks) {
                const bf16x8 kr8 = *(const bf16x8*)(kbr + krow + ks * 32 + lg * 8);
                const bf16x8 ki8 = *(const bf16x8*)(kbi + krow + ks * 32 + lg * 8);
                str[t] = MFMA16(kr8, aqr[ks], str[t]);
                str[t] = MFMA16(ki8, aqi[ks], str[t]);
                sti[t] = MFMA16(ki8, aqr[ks], sti[t]);
                sti[t] = MFMA16(kr8, aqin[ks], sti[t]);
            }
        }
        float p[8];
        float tmax = -1e30f;
#pragma unroll
        for (int t = 0; t < 2; ++t)
#pragma unroll
            for (int j = 0; j < 4; ++j) {
                const float sr = str[t][j], si = sti[t][j];
                const float m = sqrtf(sr * sr + si * si + 1e-8f) * 0.125f;
                p[t * 4 + j] = m;
                tmax = fmaxf(tmax, m);
            }
        tmax = fmaxf(tmax, __shfl_xor(tmax, 16));
        tmax = fmaxf(tmax, __shfl_xor(tmax, 32));
        const float mnew = fmaxf(mrun, tmax);
        const float corr = expf(mrun - mnew);
        float ls = 0.0f;
#pragma unroll
        for (int q2 = 0; q2 < 8; ++q2) {
            p[q2] = expf(p[q2] - mnew);
            ls += p[q2];
        }
        ls += __shfl_xor(ls, 16);
        ls += __shfl_xor(ls, 32);
        lrun = lrun * corr + ls;
        mrun = mnew;

        float cj[4];
#pragma unroll
        for (int j = 0; j < 4; ++j) cj[j] = __shfl(corr, lg * 4 + j);
#pragma unroll
        for (int d = 0; d < 4; ++d)
#pragma unroll
            for (int j = 0; j < 4; ++j) {
                our[d][j] *= cj[j];
                oui[d][j] *= cj[j];
            }

        const int buf = kt & 1;
        bf16x4 pk0, pk1;
#pragma unroll
        for (int j = 0; j < 4; ++j) {
            pk0[j] = (bf16)p[j];
            pk1[j] = (bf16)p[4 + j];
        }
        *(bf16x4*)(&P[buf][lr][lg * 4]) = pk0;
        *(bf16x4*)(&P[buf][lr][16 + lg * 4]) = pk1;
        __syncthreads();
        const bf16x8 pf = *(const bf16x8*)(&P[buf][lr][lg * 8]);
#pragma unroll
        for (int d = 0; d < 4; ++d) {
            const size_t vo = (size_t)(d * 16 + lr) * 2048 + kt * 32 + lg * 8;
            const bf16x8 vr8 = *(const bf16x8*)(vbr + vo);
            const bf16x8 vi8 = *(const bf16x8*)(vbi + vo);
            our[d] = MFMA16(pf, vr8, our[d]);
            oui[d] = MFMA16(pf, vi8, oui[d]);
        }
    }

    float linv[4];
#pragma unroll
    for (int j = 0; j < 4; ++j) linv[j] = 1.0f / __shfl(lrun, lg * 4 + j);
#pragma unroll
    for (int d = 0; d < 4; ++d)
#pragma unroll
        for (int j = 0; j < 4; ++j) {
            const int row = b * 2048 + qb * 16 + lg * 4 + j;
            const int col = h * 64 + d * 16 + lr;
            aor[(size_t)row * 768 + col] = (bf16)(our[d][j] * linv[j]);
            aoi[(size_t)row * 768 + col] = (bf16)(oui[d][j] * linv[j]);
        }
}

// ---------------------------------------------------------------------------
// host launch
// ---------------------------------------------------------------------------
extern "C" void kernel_launch(void* const* d_in, const int* in_sizes, int n_in,
                              void* d_out, int out_size, void* d_ws, size_t ws_size,
                              hipStream_t stream) {
    const float* x      = (const float*)d_in[0];
    const float* n1g    = (const float*)d_in[1];
    const float* n1b    = (const float*)d_in[2];
    const float* qkvwr  = (const float*)d_in[3];
    const float* qkvwi  = (const float*)d_in[4];
    const float* qkvbr  = (const float*)d_in[5];
    const float* qkvbi  = (const float*)d_in[6];
    const float* projwr = (const float*)d_in[7];
    const float* projwi = (const float*)d_in[8];
    const float* projbr = (const float*)d_in[9];
    const float* projbi = (const float*)d_in[10];
    const float* n2g    = (const float*)d_in[11];
    const float* n2b    = (const float*)d_in[12];
    const float* fc1wr  = (const float*)d_in[13];
    const float* fc1wi  = (const float*)d_in[14];
    const float* fc1br  = (const float*)d_in[15];
    const float* fc1bi  = (const float*)d_in[16];
    const float* fc2wr  = (const float*)d_in[17];
    const float* fc2wi  = (const float*)d_in[18];
    const float* fc2br  = (const float*)d_in[19];
    const float* fc2bi  = (const float*)d_in[20];

    const int M = 4096, E = 768, E3 = 2304, HH = 1536;

    char* base = (char*)d_ws;
    size_t off = 0;
    auto alloc = [&](size_t bytes) -> void* {
        void* p = base + off;
        off += (bytes + 255) & ~(size_t)255;
        return p;
    };
    float* xr  = (float*)alloc((size_t)M * E * 4);
    float* xi  = (float*)alloc((size_t)M * E * 4);
    float* xr2 = (float*)alloc((size_t)M * E * 4);
    float* xi2 = (float*)alloc((size_t)M * E * 4);
    bf16* nr   = (bf16*)alloc((size_t)M * E * 2);
    bf16* ni   = (bf16*)alloc((size_t)M * E * 2);
    bf16* wqr  = (bf16*)alloc((size_t)E3 * E * 2);
    bf16* wqi  = (bf16*)alloc((size_t)E3 * E * 2);
    bf16* wpr  = (bf16*)alloc((size_t)E * E * 2);
    bf16* wpi  = (bf16*)alloc((size_t)E * E * 2);
    bf16* w1r  = (bf16*)alloc((size_t)HH * E * 2);
    bf16* w1i  = (bf16*)alloc((size_t)HH * E * 2);
    bf16* w2r  = (bf16*)alloc((size_t)E * HH * 2);
    bf16* w2i  = (bf16*)alloc((size_t)E * HH * 2);
    bf16* qkr  = (bf16*)alloc((size_t)M * E3 * 2);
    bf16* qki  = (bf16*)alloc((size_t)M * E3 * 2);
    bf16* vtr  = (bf16*)alloc((size_t)24 * 64 * 2048 * 2);
    bf16* vti  = (bf16*)alloc((size_t)24 * 64 * 2048 * 2);
    bf16* aor  = (bf16*)alloc((size_t)M * E * 2);
    bf16* aoi  = (bf16*)alloc((size_t)M * E * 2);
    bf16* hr   = (bf16*)alloc((size_t)M * HH * 2);
    bf16* hi   = (bf16*)alloc((size_t)M * HH * 2);

    if (off > ws_size) {
        // unmistakable sentinel: workspace too small
        fill_kernel<<<1024, 256, 0, stream>>>((float*)d_out, 1.0e9f, out_size);
        return;
    }

    // split input into planes
    splitx_kernel<<<2048, 256, 0, stream>>>((const float2*)x, xr, xi, M * E);
    // weights -> bf16
    cvt_kernel<<<1024, 256, 0, stream>>>(qkvwr, wqr, E3 * E);
    cvt_kernel<<<1024, 256, 0, stream>>>(qkvwi, wqi, E3 * E);
    cvt_kernel<<<1024, 256, 0, stream>>>(projwr, wpr, E * E);
    cvt_kernel<<<1024, 256, 0, stream>>>(projwi, wpi, E * E);
    cvt_kernel<<<1024, 256, 0, stream>>>(fc1wr, w1r, HH * E);
    cvt_kernel<<<1024, 256, 0, stream>>>(fc1wi, w1i, HH * E);
    cvt_kernel<<<1024, 256, 0, stream>>>(fc2wr, w2r, E * HH);
    cvt_kernel<<<1024, 256, 0, stream>>>(fc2wi, w2i, E * HH);

    // LN1
    cln_kernel<<<M, 256, 0, stream>>>(xr, xi, n1g, n1b, nr, ni);
    // QKV
    cgemm_kernel<0><<<dim3(32, 18), 256, 0, stream>>>(nr, ni, wqr, wqi, qkvbr, qkvbi,
                                                      nullptr, nullptr, nullptr, nullptr,
                                                      qkr, qki, E3, E);
    // V transpose
    vtrans_kernel<<<dim3(32, 12, 2), 256, 0, stream>>>(qkr, qki, vtr, vti);
    // attention
    cattn_kernel<<<dim3(128, 12, 2), 64, 0, stream>>>(qkr, qki, vtr, vti, aor, aoi);
    // proj + residual -> f32 planes
    cgemm_kernel<1><<<dim3(32, 6), 256, 0, stream>>>(aor, aoi, wpr, wpi, projbr, projbi,
                                                     xr, xi, xr2, xi2, nullptr, nullptr,
                                                     E, E);
    // LN2
    cln_kernel<<<M, 256, 0, stream>>>(xr2, xi2, n2g, n2b, nr, ni);
    // FC1 + gelu
    cgemm_kernel<2><<<dim3(32, 12), 256, 0, stream>>>(nr, ni, w1r, w1i, fc1br, fc1bi,
                                                      nullptr, nullptr, nullptr, nullptr,
                                                      hr, hi, HH, E);
    // FC2 + residual -> interleaved d_out
    cgemm_kernel<3><<<dim3(32, 6), 256, 0, stream>>>(hr, hi, w2r, w2i, fc2br, fc2bi,
                                                     xr2, xi2, (float*)d_out, nullptr,
                                                     nullptr, nullptr, E, HH);
}

// Round 2
// 450.262 us; speedup vs baseline: 1.5069x; 1.5069x over previous
//
#include <hip/hip_runtime.h>
#include <cmath>

typedef __bf16 bf16;
typedef __bf16 bf16x8 __attribute__((ext_vector_type(8)));
typedef __bf16 bf16x4 __attribute__((ext_vector_type(4)));
typedef float  f32x4  __attribute__((ext_vector_type(4)));
typedef unsigned int u32x4 __attribute__((ext_vector_type(4)));

#define MFMA16(a, b, c) __builtin_amdgcn_mfma_f32_16x16x32_bf16((a), (b), (c), 0, 0, 0)
#define LOG2E 1.44269504088896f

static __device__ __forceinline__ void gl_lds16(const void* g, void* l) {
    __builtin_amdgcn_global_load_lds((const __attribute__((address_space(1))) void*)g,
                                     (__attribute__((address_space(3))) void*)l, 16, 0, 0);
}

static __device__ __forceinline__ bf16x8 bneg8(bf16x8 x) {
    u32x4 u = __builtin_bit_cast(u32x4, x);
    u = u ^ 0x80008000u;
    return __builtin_bit_cast(bf16x8, u);
}

static __device__ __forceinline__ f32x4 zero4() {
    return f32x4{0.0f, 0.0f, 0.0f, 0.0f};
}

// ---------------------------------------------------------------------------
// small utility kernels
// ---------------------------------------------------------------------------
__global__ void fill_kernel(float* p, float v, int n) {
    for (int i = blockIdx.x * blockDim.x + threadIdx.x; i < n; i += gridDim.x * blockDim.x)
        p[i] = v;
}

__global__ void splitx_kernel(const float2* __restrict__ x, float* __restrict__ xr,
                              float* __restrict__ xi, int n) {
    for (int i = blockIdx.x * blockDim.x + threadIdx.x; i < n; i += gridDim.x * blockDim.x) {
        float2 v = x[i];
        xr[i] = v.x;
        xi[i] = v.y;
    }
}

__global__ void cvt_kernel(const float* __restrict__ in, bf16* __restrict__ out, int n) {
    for (int i = blockIdx.x * blockDim.x + threadIdx.x; i < n; i += gridDim.x * blockDim.x)
        out[i] = (bf16)in[i];
}

// ---------------------------------------------------------------------------
// complex magnitude layernorm: planes (f32) -> bf16 planes
// ---------------------------------------------------------------------------
__global__ __launch_bounds__(256) void cln_kernel(
    const float* __restrict__ xr, const float* __restrict__ xi,
    const float* __restrict__ gamma, const float* __restrict__ beta,
    bf16* __restrict__ nr, bf16* __restrict__ ni) {
    __shared__ float red[4];
    const int t = threadIdx.x;
    const size_t base = (size_t)blockIdx.x * 768;

    float r[3], im[3], mg[3];
#pragma unroll
    for (int j = 0; j < 3; ++j) {
        const int f = t + j * 256;
        r[j] = xr[base + f];
        im[j] = xi[base + f];
        mg[j] = __builtin_amdgcn_sqrtf(r[j] * r[j] + im[j] * im[j] + 1e-6f);
    }
    float s = mg[0] + mg[1] + mg[2];
#pragma unroll
    for (int m = 32; m >= 1; m >>= 1) s += __shfl_xor(s, m);
    if ((t & 63) == 0) red[t >> 6] = s;
    __syncthreads();
    const float mean = (red[0] + red[1] + red[2] + red[3]) * (1.0f / 768.0f);
    __syncthreads();

    float v = 0.0f;
#pragma unroll
    for (int j = 0; j < 3; ++j) {
        const float d = mg[j] - mean;
        v += d * d;
    }
#pragma unroll
    for (int m = 32; m >= 1; m >>= 1) v += __shfl_xor(v, m);
    if ((t & 63) == 0) red[t >> 6] = v;
    __syncthreads();
    const float var = (red[0] + red[1] + red[2] + red[3]) * (1.0f / 768.0f);
    const float rstd = rsqrtf(var + 1e-6f);

#pragma unroll
    for (int j = 0; j < 3; ++j) {
        const int f = t + j * 256;
        const float sc = (mg[j] - mean) * rstd / (mg[j] + 1e-6f);
        nr[base + f] = (bf16)(gamma[2 * f] * (r[j] * sc) + beta[2 * f]);
        ni[base + f] = (bf16)(gamma[2 * f + 1] * (im[j] * sc) + beta[2 * f + 1]);
    }
}

// ---------------------------------------------------------------------------
// complex GEMM (NT) with global_load_lds staging (m97 structure)
// ---------------------------------------------------------------------------
template <int MODE>
__global__ __launch_bounds__(256, 2) void cgemm_kernel(
    const bf16* __restrict__ Ar, const bf16* __restrict__ Ai,
    const bf16* __restrict__ Wr, const bf16* __restrict__ Wi,
    const float* __restrict__ br, const float* __restrict__ bi,
    const float* __restrict__ resr, const float* __restrict__ resi,
    float* __restrict__ outFr, float* __restrict__ outFi,
    bf16* __restrict__ outBr, bf16* __restrict__ outBi,
    int N, int K) {
    __shared__ bf16 sAr[128][32];
    __shared__ bf16 sAi[128][32];
    __shared__ bf16 sBr[128][32];
    __shared__ bf16 sBi[128][32];

    const int tid = threadIdx.x;
    const int wave = tid >> 6, lane = tid & 63;
    const int lg = lane >> 4, lr = lane & 15;
    const int row0 = blockIdx.x * 128, col0 = blockIdx.y * 128;
    const int wm = (wave >> 1) * 64, wn = (wave & 1) * 64;

    // staging geometry: per plane 128 rows x 4 chunks(16B) = 8 segments of 64
    const int srow = lane >> 2;      // row within segment (0..15)
    const int sc8 = (lane & 3) * 8;  // element offset of 16B chunk

    f32x4 accr[4][4], acci[4][4];
#pragma unroll
    for (int a = 0; a < 4; ++a)
#pragma unroll
        for (int b2 = 0; b2 < 4; ++b2) {
            accr[a][b2] = zero4();
            acci[a][b2] = zero4();
        }

    for (int kt = 0; kt < K; kt += 32) {
        __syncthreads();
#pragma unroll
        for (int s = 0; s < 2; ++s) {
            const int seg = wave * 2 + s;        // 0..7
            const int row = seg * 16 + srow;     // 0..127
            const size_t ga = (size_t)(row0 + row) * K + kt + sc8;
            const size_t gb = (size_t)(col0 + row) * K + kt + sc8;
            gl_lds16(Ar + ga, &sAr[seg * 16][0]);
            gl_lds16(Ai + ga, &sAi[seg * 16][0]);
            gl_lds16(Wr + gb, &sBr[seg * 16][0]);
            gl_lds16(Wi + gb, &sBi[seg * 16][0]);
        }
        __syncthreads();

        bf16x8 ar[4], ai[4], an[4];
#pragma unroll
        for (int mt = 0; mt < 4; ++mt) {
            ar[mt] = *(const bf16x8*)(&sAr[wm + mt * 16 + lr][lg * 8]);
            ai[mt] = *(const bf16x8*)(&sAi[wm + mt * 16 + lr][lg * 8]);
            an[mt] = bneg8(ai[mt]);
        }
#pragma unroll
        for (int nt = 0; nt < 4; ++nt) {
            const bf16x8 br8 = *(const bf16x8*)(&sBr[wn + nt * 16 + lr][lg * 8]);
            const bf16x8 bi8 = *(const bf16x8*)(&sBi[wn + nt * 16 + lr][lg * 8]);
#pragma unroll
            for (int mt = 0; mt < 4; ++mt) {
                accr[mt][nt] = MFMA16(ar[mt], br8, accr[mt][nt]);
                accr[mt][nt] = MFMA16(an[mt], bi8, accr[mt][nt]);
                acci[mt][nt] = MFMA16(ar[mt], bi8, acci[mt][nt]);
                acci[mt][nt] = MFMA16(ai[mt], br8, acci[mt][nt]);
            }
        }
    }

#pragma unroll
    for (int nt = 0; nt < 4; ++nt) {
        const int col = col0 + wn + nt * 16 + lr;
        const float bre = br[col], bie = bi[col];
#pragma unroll
        for (int mt = 0; mt < 4; ++mt) {
#pragma unroll
            for (int j = 0; j < 4; ++j) {
                const int row = row0 + wm + mt * 16 + lg * 4 + j;
                float vr = accr[mt][nt][j] + bre;
                float vi = acci[mt][nt][j] + bie;
                const size_t o = (size_t)row * N + col;
                if (MODE == 0) {
                    outBr[o] = (bf16)vr;
                    outBi[o] = (bf16)vi;
                } else if (MODE == 1) {
                    outFr[o] = resr[o] + vr;
                    outFi[o] = resi[o] + vi;
                } else if (MODE == 2) {
                    vr = 0.5f * vr * (1.0f + erff(vr * 0.70710678118654752f));
                    vi = 0.5f * vi * (1.0f + erff(vi * 0.70710678118654752f));
                    outBr[o] = (bf16)vr;
                    outBi[o] = (bf16)vi;
                } else {
                    const size_t ro = (size_t)row * 768 + col;
                    outFr[(size_t)row * 1536 + 2 * col]     = resr[ro] + vr;
                    outFr[(size_t)row * 1536 + 2 * col + 1] = resi[ro] + vi;
                }
            }
        }
    }
}

// ---------------------------------------------------------------------------
// transpose V slice of qkv into [B*nH][64 d][2048 n] bf16 planes
// ---------------------------------------------------------------------------
__global__ __launch_bounds__(256) void vtrans_kernel(
    const bf16* __restrict__ qkvr, const bf16* __restrict__ qkvi,
    bf16* __restrict__ vtr, bf16* __restrict__ vti) {
    __shared__ bf16 sr[64][65];
    __shared__ bf16 si[64][65];
    const int t = threadIdx.x;
    const int nb = blockIdx.x, h = blockIdx.y, b = blockIdx.z;
    const size_t ld = 2304;
    const bf16* srcr = qkvr + (size_t)(b * 2048 + nb * 64) * ld + 1536 + h * 64;
    const bf16* srci = qkvi + (size_t)(b * 2048 + nb * 64) * ld + 1536 + h * 64;
#pragma unroll
    for (int j = 0; j < 16; ++j) {
        const int idx = t + 256 * j;
        const int n = idx >> 6, d = idx & 63;
        sr[n][d] = srcr[(size_t)n * ld + d];
        si[n][d] = srci[(size_t)n * ld + d];
    }
    __syncthreads();
    bf16* dstr = vtr + (size_t)(b * 12 + h) * 64 * 2048 + nb * 64;
    bf16* dsti = vti + (size_t)(b * 12 + h) * 64 * 2048 + nb * 64;
#pragma unroll
    for (int j = 0; j < 16; ++j) {
        const int idx = t + 256 * j;
        const int d = idx >> 6, n = idx & 63;
        dstr[(size_t)d * 2048 + n] = sr[n][d];
        dsti[(size_t)d * 2048 + n] = si[n][d];
    }
}

// ---------------------------------------------------------------------------
// fused complex flash attention, 4 waves/block, 64-key tiles,
// K/V double-buffered in LDS via global_load_lds with source-side XOR swizzle
// ---------------------------------------------------------------------------
__global__ __launch_bounds__(256, 2) void cattn_kernel(
    const bf16* __restrict__ qkvr, const bf16* __restrict__ qkvi,
    const bf16* __restrict__ vtr, const bf16* __restrict__ vti,
    bf16* __restrict__ aor, bf16* __restrict__ aoi) {
    __shared__ bf16 sK[2][2][64][64];  // [buf][r/i][key][d]   (chunk-swizzled)
    __shared__ bf16 sV[2][2][64][64];  // [buf][r/i][d][key]   (chunk-swizzled)
    __shared__ bf16 sP[4][16][72];     // per-wave P, padded rows (144B)

    const int tid = threadIdx.x;
    const int w = tid >> 6, lane = tid & 63;
    const int lg = lane >> 4, lr = lane & 15;
    const int qb = blockIdx.x, h = blockIdx.y, b = blockIdx.z;
    const int ld = 2304;
    const int kx = lr & 7;

    // staging lane constants: lane -> (row srow in segment, swizzled chunk scg)
    const int srow = lane >> 3;
    const int scg8 = ((lane & 7) ^ srow) * 8;

    const bf16* kbr = qkvr + (size_t)b * 2048 * ld + 768 + h * 64;
    const bf16* kbi = qkvi + (size_t)b * 2048 * ld + 768 + h * 64;
    const bf16* vbr = vtr + (size_t)(b * 12 + h) * 64 * 2048;
    const bf16* vbi = vti + (size_t)(b * 12 + h) * 64 * 2048;

    auto stage = [&](int buf, int kt) {
#pragma unroll
        for (int s = 0; s < 2; ++s) {
            const int seg = w * 2 + s;       // 0..7
            const int row = seg * 8 + srow;  // 0..63
            gl_lds16(kbr + (size_t)(kt * 64 + row) * ld + scg8, &sK[buf][0][seg * 8][0]);
            gl_lds16(kbi + (size_t)(kt * 64 + row) * ld + scg8, &sK[buf][1][seg * 8][0]);
            gl_lds16(vbr + (size_t)row * 2048 + kt * 64 + scg8, &sV[buf][0][seg * 8][0]);
            gl_lds16(vbi + (size_t)row * 2048 + kt * 64 + scg8, &sV[buf][1][seg * 8][0]);
        }
    };

    stage(0, 0);

    // Q fragments (16 q-rows per wave), hoisted to registers
    const size_t qoff = (size_t)(b * 2048 + qb * 64 + w * 16 + lr) * ld + h * 64;
    bf16x8 aqr[2], aqi[2], aqin[2];
#pragma unroll
    for (int ks = 0; ks < 2; ++ks) {
        aqr[ks] = *(const bf16x8*)(qkvr + qoff + ks * 32 + lg * 8);
        aqi[ks] = *(const bf16x8*)(qkvi + qoff + ks * 32 + lg * 8);
        aqin[ks] = bneg8(aqi[ks]);
    }

    f32x4 our[4], oui[4];
#pragma unroll
    for (int d = 0; d < 4; ++d) {
        our[d] = zero4();
        oui[d] = zero4();
    }
    float mrun = -1e30f, lrun = 0.0f;

    __syncthreads();  // buf0 staged (barrier drains vmcnt)

    for (int kt = 0; kt < 32; ++kt) {
        const int cur = kt & 1;
        if (kt < 31) stage(cur ^ 1, kt + 1);  // fire-and-forget prefetch

        // ---- QK^T: scores for 64 keys x 16 queries ----
        f32x4 str[4], sti[4];
#pragma unroll
        for (int t = 0; t < 4; ++t) {
            str[t] = zero4();
            sti[t] = zero4();
        }
#pragma unroll
        for (int t = 0; t < 4; ++t) {
#pragma unroll
            for (int ks = 0; ks < 2; ++ks) {
                const int ch = (((ks << 2) | lg) ^ kx) << 3;
                const bf16x8 kr8 = *(const bf16x8*)(&sK[cur][0][t * 16 + lr][ch]);
                const bf16x8 ki8 = *(const bf16x8*)(&sK[cur][1][t * 16 + lr][ch]);
                str[t] = MFMA16(kr8, aqr[ks], str[t]);
                str[t] = MFMA16(ki8, aqi[ks], str[t]);
                sti[t] = MFMA16(ki8, aqr[ks], sti[t]);
                sti[t] = MFMA16(kr8, aqin[ks], sti[t]);
            }
        }

        // ---- magnitude + online softmax (per lane: q=lr, 16 keys) ----
        float p[16];
        float tmax = -1e30f;
#pragma unroll
        for (int t = 0; t < 4; ++t)
#pragma unroll
            for (int j = 0; j < 4; ++j) {
                const float sr = str[t][j], si = sti[t][j];
                const float m = __builtin_amdgcn_sqrtf(sr * sr + si * si + 1e-8f) * 0.125f;
                p[t * 4 + j] = m;
                tmax = fmaxf(tmax, m);
            }
        tmax = fmaxf(tmax, __shfl_xor(tmax, 16));
        tmax = fmaxf(tmax, __shfl_xor(tmax, 32));

        if (!__all(tmax <= mrun)) {
            const float mnew = fmaxf(mrun, tmax);
            const float corr = __builtin_amdgcn_exp2f((mrun - mnew) * LOG2E);
            float cj[4];
#pragma unroll
            for (int j = 0; j < 4; ++j) cj[j] = __shfl(corr, lg * 4 + j);
#pragma unroll
            for (int d = 0; d < 4; ++d)
#pragma unroll
                for (int j = 0; j < 4; ++j) {
                    our[d][j] *= cj[j];
                    oui[d][j] *= cj[j];
                }
            lrun *= corr;
            mrun = mnew;
        }

        float ls = 0.0f;
#pragma unroll
        for (int i = 0; i < 16; ++i) {
            p[i] = __builtin_amdgcn_exp2f((p[i] - mrun) * LOG2E);
            ls += p[i];
        }
        ls += __shfl_xor(ls, 16);
        ls += __shfl_xor(ls, 32);
        lrun += ls;

        // ---- P -> LDS (bf16), padded rows ----
#pragma unroll
        for (int t = 0; t < 4; ++t) {
            bf16x4 pk;
#pragma unroll
            for (int j = 0; j < 4; ++j) pk[j] = (bf16)p[t * 4 + j];
            *(bf16x4*)(&sP[w][lr][t * 16 + lg * 4]) = pk;
        }
        const bf16x8 pf0 = *(const bf16x8*)(&sP[w][lr][lg * 8]);
        const bf16x8 pf1 = *(const bf16x8*)(&sP[w][lr][32 + lg * 8]);

        // ---- PV ----
#pragma unroll
        for (int d = 0; d < 4; ++d) {
#pragma unroll
            for (int ks2 = 0; ks2 < 2; ++ks2) {
                const int ch = (((ks2 << 2) | lg) ^ kx) << 3;
                const bf16x8 vr8 = *(const bf16x8*)(&sV[cur][0][d * 16 + lr][ch]);
                const bf16x8 vi8 = *(const bf16x8*)(&sV[cur][1][d * 16 + lr][ch]);
                const bf16x8 pf = ks2 ? pf1 : pf0;
                our[d] = MFMA16(pf, vr8, our[d]);
                oui[d] = MFMA16(pf, vi8, oui[d]);
            }
        }
        __syncthreads();  // drains staging vmcnt + all LDS reads before overwrite
    }

    float linv[4];
#pragma unroll
    for (int j = 0; j < 4; ++j) {
        const float lj = __shfl(lrun, lg * 4 + j);
        linv[j] = __builtin_amdgcn_rcpf(lj);
    }
#pragma unroll
    for (int d = 0; d < 4; ++d)
#pragma unroll
        for (int j = 0; j < 4; ++j) {
            const int row = b * 2048 + qb * 64 + w * 16 + lg * 4 + j;
            const int col = h * 64 + d * 16 + lr;
            aor[(size_t)row * 768 + col] = (bf16)(our[d][j] * linv[j]);
            aoi[(size_t)row * 768 + col] = (bf16)(oui[d][j] * linv[j]);
        }
}

// ---------------------------------------------------------------------------
// host launch
// ---------------------------------------------------------------------------
extern "C" void kernel_launch(void* const* d_in, const int* in_sizes, int n_in,
                              void* d_out, int out_size, void* d_ws, size_t ws_size,
                              hipStream_t stream) {
    const float* x      = (const float*)d_in[0];
    const float* n1g    = (const float*)d_in[1];
    const float* n1b    = (const float*)d_in[2];
    const float* qkvwr  = (const float*)d_in[3];
    const float* qkvwi  = (const float*)d_in[4];
    const float* qkvbr  = (const float*)d_in[5];
    const float* qkvbi  = (const float*)d_in[6];
    const float* projwr = (const float*)d_in[7];
    const float* projwi = (const float*)d_in[8];
    const float* projbr = (const float*)d_in[9];
    const float* projbi = (const float*)d_in[10];
    const float* n2g    = (const float*)d_in[11];
    const float* n2b    = (const float*)d_in[12];
    const float* fc1wr  = (const float*)d_in[13];
    const float* fc1wi  = (const float*)d_in[14];
    const float* fc1br  = (const float*)d_in[15];
    const float* fc1bi  = (const float*)d_in[16];
    const float* fc2wr  = (const float*)d_in[17];
    const float* fc2wi  = (const float*)d_in[18];
    const float* fc2br  = (const float*)d_in[19];
    const float* fc2bi  = (const float*)d_in[20];

    const int M = 4096, E = 768, E3 = 2304, HH = 1536;

    char* base = (char*)d_ws;
    size_t off = 0;
    auto alloc = [&](size_t bytes) -> void* {
        void* p = base + off;
        off += (bytes + 255) & ~(size_t)255;
        return p;
    };
    float* xr  = (float*)alloc((size_t)M * E * 4);
    float* xi  = (float*)alloc((size_t)M * E * 4);
    float* xr2 = (float*)alloc((size_t)M * E * 4);
    float* xi2 = (float*)alloc((size_t)M * E * 4);
    bf16* nr   = (bf16*)alloc((size_t)M * E * 2);
    bf16* ni   = (bf16*)alloc((size_t)M * E * 2);
    bf16* wqr  = (bf16*)alloc((size_t)E3 * E * 2);
    bf16* wqi  = (bf16*)alloc((size_t)E3 * E * 2);
    bf16* wpr  = (bf16*)alloc((size_t)E * E * 2);
    bf16* wpi  = (bf16*)alloc((size_t)E * E * 2);
    bf16* w1r  = (bf16*)alloc((size_t)HH * E * 2);
    bf16* w1i  = (bf16*)alloc((size_t)HH * E * 2);
    bf16* w2r  = (bf16*)alloc((size_t)E * HH * 2);
    bf16* w2i  = (bf16*)alloc((size_t)E * HH * 2);
    bf16* qkr  = (bf16*)alloc((size_t)M * E3 * 2);
    bf16* qki  = (bf16*)alloc((size_t)M * E3 * 2);
    bf16* vtr  = (bf16*)alloc((size_t)24 * 64 * 2048 * 2);
    bf16* vti  = (bf16*)alloc((size_t)24 * 64 * 2048 * 2);
    bf16* aor  = (bf16*)alloc((size_t)M * E * 2);
    bf16* aoi  = (bf16*)alloc((size_t)M * E * 2);
    bf16* hr   = (bf16*)alloc((size_t)M * HH * 2);
    bf16* hi   = (bf16*)alloc((size_t)M * HH * 2);

    if (off > ws_size) {
        fill_kernel<<<1024, 256, 0, stream>>>((float*)d_out, 1.0e9f, out_size);
        return;
    }

    splitx_kernel<<<2048, 256, 0, stream>>>((const float2*)x, xr, xi, M * E);
    cvt_kernel<<<1024, 256, 0, stream>>>(qkvwr, wqr, E3 * E);
    cvt_kernel<<<1024, 256, 0, stream>>>(qkvwi, wqi, E3 * E);
    cvt_kernel<<<1024, 256, 0, stream>>>(projwr, wpr, E * E);
    cvt_kernel<<<1024, 256, 0, stream>>>(projwi, wpi, E * E);
    cvt_kernel<<<1024, 256, 0, stream>>>(fc1wr, w1r, HH * E);
    cvt_kernel<<<1024, 256, 0, stream>>>(fc1wi, w1i, HH * E);
    cvt_kernel<<<1024, 256, 0, stream>>>(fc2wr, w2r, E * HH);
    cvt_kernel<<<1024, 256, 0, stream>>>(fc2wi, w2i, E * HH);

    // LN1
    cln_kernel<<<M, 256, 0, stream>>>(xr, xi, n1g, n1b, nr, ni);
    // QKV
    cgemm_kernel<0><<<dim3(32, 18), 256, 0, stream>>>(nr, ni, wqr, wqi, qkvbr, qkvbi,
                                                      nullptr, nullptr, nullptr, nullptr,
                                                      qkr, qki, E3, E);
    // V transpose
    vtrans_kernel<<<dim3(32, 12, 2), 256, 0, stream>>>(qkr, qki, vtr, vti);
    // attention
    cattn_kernel<<<dim3(32, 12, 2), 256, 0, stream>>>(qkr, qki, vtr, vti, aor, aoi);
    // proj + residual -> f32 planes
    cgemm_kernel<1><<<dim3(32, 6), 256, 0, stream>>>(aor, aoi, wpr, wpi, projbr, projbi,
                                                     xr, xi, xr2, xi2, nullptr, nullptr,
                                                     E, E);
    // LN2
    cln_kernel<<<M, 256, 0, stream>>>(xr2, xi2, n2g, n2b, nr, ni);
    // FC1 + gelu
    cgemm_kernel<2><<<dim3(32, 12), 256, 0, stream>>>(nr, ni, w1r, w1i, fc1br, fc1bi,
                                                      nullptr, nullptr, nullptr, nullptr,
                                                      hr, hi, HH, E);
    // FC2 + residual -> interleaved d_out
    cgemm_kernel<3><<<dim3(32, 6), 256, 0, stream>>>(hr, hi, w2r, w2i, fc2br, fc2bi,
                                                     xr2, xi2, (float*)d_out, nullptr,
                                                     nullptr, nullptr, E, HH);
}